// Round 3
// baseline (714.080 us; speedup 1.0000x reference)
//
#include <hip/hip_runtime.h>
#include <hip/hip_bf16.h>
#include <stdint.h>

#define N_NODES 100000
#define N_EDGES 1280000
#define IN_DIM  256
#define OUT_DIM 64

typedef __attribute__((ext_vector_type(4))) float f32x4;

// ---------------------------------------------------------------------------
// GEMM (fp32 VALU): pre[N_NODES][64] = X[N_NODES][256] @ W[256][64]
// Block = 256 threads = 4 waves; block covers 64 rows.
// Wave w handles rows [base + 16w, base + 16w + 16), lane n = column.
// W staged in LDS transposed [n][k] (pad 268: 16B-aligned rows, bounded bank
// conflicts); x addresses are wave-uniform -> scalar loads (SMEM path).
// ---------------------------------------------------------------------------
__global__ __launch_bounds__(256) void gemm_kernel(const float* __restrict__ x,
                                                   const float* __restrict__ w,
                                                   float* __restrict__ pre) {
    __shared__ __align__(16) float wsh[OUT_DIM][IN_DIM + 12];   // [n][k], 268 floats/row

    const int tid = threadIdx.x;
    // W is [256][64] row-major: element i -> k=i>>6, n=i&63. Coalesced read.
    for (int i = tid; i < IN_DIM * OUT_DIM; i += 256) {
        wsh[i & 63][i >> 6] = w[i];
    }
    __syncthreads();

    const int n = tid & 63;
    int rgrp = tid >> 6;                               // 0..3, uniform per wave
    rgrp = __builtin_amdgcn_readfirstlane(rgrp);       // make provably uniform
    const int rbase = blockIdx.x * 64 + rgrp * 16;

    // Precompute clamped row base pointers (wave-uniform -> SGPRs)
    const float* xp[16];
    #pragma unroll
    for (int i = 0; i < 16; ++i) {
        int r = rbase + i;
        r = r < N_NODES ? r : N_NODES - 1;
        xp[i] = x + (size_t)r * IN_DIM;
    }

    float acc[16];
    #pragma unroll
    for (int i = 0; i < 16; ++i) acc[i] = 0.0f;

    #pragma unroll 4
    for (int k0 = 0; k0 < IN_DIM; k0 += 4) {
        f32x4 wv = *(const f32x4*)&wsh[n][k0];         // per-lane column weights
        #pragma unroll
        for (int i = 0; i < 16; ++i) {
            f32x4 xv = *(const f32x4*)(xp[i] + k0);    // wave-uniform (scalar) load
            acc[i] += xv.x * wv.x + xv.y * wv.y + xv.z * wv.z + xv.w * wv.w;
        }
    }

    #pragma unroll
    for (int i = 0; i < 16; ++i) {
        int r = rbase + i;
        if (r < N_NODES) pre[(size_t)r * OUT_DIM + n] = acc[i];
    }
}

// ---------------------------------------------------------------------------
// Scatter: edge e, lane j: accum[rows[e]][j] += pre[cols[e]][j] * vals[e]
// 64 lanes per edge -> coalesced 256B gather + 256B fp32 atomic scatter.
// ---------------------------------------------------------------------------
__global__ __launch_bounds__(256) void scatter_kernel(const int* __restrict__ rows,
                                                      const int* __restrict__ cols,
                                                      const float* __restrict__ vals,
                                                      const float* __restrict__ pre,
                                                      float* __restrict__ accum) {
    const int t = blockIdx.x * 256 + threadIdx.x;
    const int e = t >> 6;
    const int j = t & 63;
    if (e < N_EDGES) {
        const int c = cols[e];
        const int r = rows[e];
        const float v = vals[e];
        const float g = pre[(size_t)c * OUT_DIM + j] * v;
        atomicAdd(&accum[(size_t)r * OUT_DIM + j], g);
    }
}

// ---------------------------------------------------------------------------
// Finalize: out[i] = relu(accum[i] + bias[dim]),  fp32 out, 4 elems/thread
// ---------------------------------------------------------------------------
__global__ __launch_bounds__(256) void finalize_kernel(const float* __restrict__ accum,
                                                       const float* __restrict__ bias,
                                                       float* __restrict__ out) {
    const int i = blockIdx.x * 256 + threadIdx.x;      // 4 consecutive elems/thread
    if (i >= N_NODES * OUT_DIM / 4) return;
    const int n0 = (i & 15) * 4;                       // dim index of first elem
    f32x4 a = *(const f32x4*)(accum + (size_t)i * 4);
    f32x4 o;
    #pragma unroll
    for (int q = 0; q < 4; ++q) {
        float vv = a[q] + bias[n0 + q];
        o[q] = vv > 0.0f ? vv : 0.0f;
    }
    *(f32x4*)(out + (size_t)i * 4) = o;
}

extern "C" void kernel_launch(void* const* d_in, const int* in_sizes, int n_in,
                              void* d_out, int out_size, void* d_ws, size_t ws_size,
                              hipStream_t stream) {
    const float* x    = (const float*)d_in[0];
    const int* rows   = (const int*)d_in[1];
    const int* cols   = (const int*)d_in[2];
    const float* vals = (const float*)d_in[3];
    const float* w    = (const float*)d_in[4];
    const float* bias = (const float*)d_in[5];
    float* out        = (float*)d_out;

    float* accum = (float*)d_ws;                               // 25.6 MB
    float* pre   = accum + (size_t)N_NODES * OUT_DIM;          // 25.6 MB

    hipMemsetAsync(accum, 0, (size_t)N_NODES * OUT_DIM * sizeof(float), stream);

    gemm_kernel<<<(N_NODES + 63) / 64, 256, 0, stream>>>(x, w, pre);

    scatter_kernel<<<(N_EDGES * 64) / 256, 256, 0, stream>>>(rows, cols, vals, pre, accum);

    finalize_kernel<<<(N_NODES * OUT_DIM / 4 + 255) / 256, 256, 0, stream>>>(accum, bias, out);
}

// Round 4
// 478.861 us; speedup vs baseline: 1.4912x; 1.4912x over previous
//
#include <hip/hip_runtime.h>
#include <hip/hip_bf16.h>
#include <stdint.h>

#define N_NODES 100000
#define N_EDGES 1280000
#define IN_DIM  256
#define OUT_DIM 64

typedef __attribute__((ext_vector_type(8))) short bf16x8;
typedef __attribute__((ext_vector_type(4))) float f32x4;

__device__ __forceinline__ unsigned short f32_to_bf16(float f) {
    union { float f; unsigned int u; } c; c.f = f;
    unsigned int u = c.u;
    u += 0x7fffu + ((u >> 16) & 1u);   // round-to-nearest-even
    return (unsigned short)(u >> 16);
}

// ---------------------------------------------------------------------------
// GEMM: pre[N_NODES][64] (fp32) = X[N,256](fp32->bf16) @ W[256,64](fp32->bf16)
// via mfma_f32_16x16x32_bf16. Block = 4 waves = 64 rows; wave = 16 rows x 64
// cols (4 n-tiles). W staged in LDS in EXACT B-fragment order so each B-read
// is ds_read_b128 at lane*16B (conflict-free). A-fragment: 2 float4 global
// loads + RNE pack. Fragment layouts per verified m89 mappings:
//   A[m=lane&15][k=quad*8+j], B[k=quad*8+j][n=lane&15], C/D: col=lane&15,
//   row=quad*4+reg.
// ---------------------------------------------------------------------------
__global__ __launch_bounds__(256) void gemm_kernel(const float* __restrict__ x,
                                                   const float* __restrict__ w,
                                                   float* __restrict__ pre) {
    // fragment-ordered W: [kt][t][lane][8] -> 8*4*64*8 = 16384 bf16 = 32 KB
    __shared__ __align__(16) unsigned short wt[8 * 4 * 64 * 8];

    const int tid = threadIdx.x;
    // W[k][n] (row-major [256][64]) -> wt[((kt*4+t)*64 + q*16+l)*8 + j]
    // where kt=k>>5, q=(k>>3)&3, j=k&7, t=n>>4, l=n&15.
    for (int i = tid; i < IN_DIM * OUT_DIM; i += 256) {
        const int k = i >> 6, n = i & 63;
        const int kt = k >> 5, q = (k >> 3) & 3, j = k & 7;
        const int t = n >> 4, l = n & 15;
        wt[((kt * 4 + t) * 64 + q * 16 + l) * 8 + j] = f32_to_bf16(w[i]);
    }
    __syncthreads();

    const int wave = tid >> 6;
    const int lane = tid & 63;
    const int ln16 = lane & 15;
    const int quad = lane >> 4;

    const int row = blockIdx.x * 64 + wave * 16 + ln16;     // A-operand row m
    const int arow = row < N_NODES ? row : N_NODES - 1;     // clamp for safe load
    const float* xrow = x + (size_t)arow * IN_DIM;

    f32x4 acc[4] = {};

    #pragma unroll
    for (int kt = 0; kt < 8; ++kt) {
        const int k0 = kt * 32;
        f32x4 xa = *(const f32x4*)(xrow + k0 + quad * 8);
        f32x4 xb = *(const f32x4*)(xrow + k0 + quad * 8 + 4);
        bf16x8 a;
        #pragma unroll
        for (int q = 0; q < 4; ++q) {
            a[q]     = (short)f32_to_bf16(xa[q]);
            a[q + 4] = (short)f32_to_bf16(xb[q]);
        }
        #pragma unroll
        for (int t = 0; t < 4; ++t) {
            bf16x8 b = *(const bf16x8*)(&wt[((kt * 4 + t) * 64 + lane) * 8]);
            acc[t] = __builtin_amdgcn_mfma_f32_16x16x32_bf16(a, b, acc[t], 0, 0, 0);
        }
    }

    // C/D: col = lane&15, row = quad*4 + reg
    const int rbase = blockIdx.x * 64 + wave * 16 + quad * 4;
    #pragma unroll
    for (int t = 0; t < 4; ++t) {
        #pragma unroll
        for (int r = 0; r < 4; ++r) {
            int rr = rbase + r;
            if (rr < N_NODES)
                pre[(size_t)rr * OUT_DIM + t * 16 + ln16] = acc[t][r];
        }
    }
}

// ---------------------------------------------------------------------------
// Scatter: edge e, lane j: accum[rows[e]][j] += pre[cols[e]][j] * vals[e]
// 64 lanes per edge -> coalesced 256B gather + 256B fp32 atomic scatter.
// ---------------------------------------------------------------------------
__global__ __launch_bounds__(256) void scatter_kernel(const int* __restrict__ rows,
                                                      const int* __restrict__ cols,
                                                      const float* __restrict__ vals,
                                                      const float* __restrict__ pre,
                                                      float* __restrict__ accum) {
    const int t = blockIdx.x * 256 + threadIdx.x;
    const int e = t >> 6;
    const int j = t & 63;
    if (e < N_EDGES) {
        const int c = cols[e];
        const int r = rows[e];
        const float v = vals[e];
        const float g = pre[(size_t)c * OUT_DIM + j] * v;
        atomicAdd(&accum[(size_t)r * OUT_DIM + j], g);
    }
}

// ---------------------------------------------------------------------------
// Finalize: out[i] = relu(accum[i] + bias[dim]), fp32 out, 4 elems/thread
// ---------------------------------------------------------------------------
__global__ __launch_bounds__(256) void finalize_kernel(const float* __restrict__ accum,
                                                       const float* __restrict__ bias,
                                                       float* __restrict__ out) {
    const int i = blockIdx.x * 256 + threadIdx.x;      // 4 consecutive elems/thread
    if (i >= N_NODES * OUT_DIM / 4) return;
    const int n0 = (i & 15) * 4;                       // dim index of first elem
    f32x4 a = *(const f32x4*)(accum + (size_t)i * 4);
    f32x4 o;
    #pragma unroll
    for (int q = 0; q < 4; ++q) {
        float vv = a[q] + bias[n0 + q];
        o[q] = vv > 0.0f ? vv : 0.0f;
    }
    *(f32x4*)(out + (size_t)i * 4) = o;
}

extern "C" void kernel_launch(void* const* d_in, const int* in_sizes, int n_in,
                              void* d_out, int out_size, void* d_ws, size_t ws_size,
                              hipStream_t stream) {
    const float* x    = (const float*)d_in[0];
    const int* rows   = (const int*)d_in[1];
    const int* cols   = (const int*)d_in[2];
    const float* vals = (const float*)d_in[3];
    const float* w    = (const float*)d_in[4];
    const float* bias = (const float*)d_in[5];
    float* out        = (float*)d_out;

    float* accum = (float*)d_ws;                               // 25.6 MB
    float* pre   = accum + (size_t)N_NODES * OUT_DIM;          // 25.6 MB

    hipMemsetAsync(accum, 0, (size_t)N_NODES * OUT_DIM * sizeof(float), stream);

    gemm_kernel<<<(N_NODES + 63) / 64, 256, 0, stream>>>(x, w, pre);

    scatter_kernel<<<(N_EDGES * 64) / 256, 256, 0, stream>>>(rows, cols, vals, pre, accum);

    finalize_kernel<<<(N_NODES * OUT_DIM / 4 + 255) / 256, 256, 0, stream>>>(accum, bias, out);
}

// Round 5
// 412.620 us; speedup vs baseline: 1.7306x; 1.1605x over previous
//
#include <hip/hip_runtime.h>
#include <hip/hip_bf16.h>
#include <stdint.h>

#define N_NODES 100000
#define N_EDGES 1280000
#define IN_DIM  256
#define OUT_DIM 64
#define NB1     98          // ceil(100000/1024) scan blocks

typedef __attribute__((ext_vector_type(8))) short bf16x8;
typedef __attribute__((ext_vector_type(4))) float f32x4;
typedef __attribute__((ext_vector_type(4))) unsigned short u16x4;

__device__ __forceinline__ unsigned short f32_to_bf16(float f) {
    union { float f; unsigned int u; } c; c.f = f;
    unsigned int u = c.u;
    u += 0x7fffu + ((u >> 16) & 1u);   // RNE
    return (unsigned short)(u >> 16);
}

// ---------------------------------------------------------------------------
// GEMM: pre[N][64] fp32 = bf16(X[N][256]) @ bf16(W[256][64]), MFMA 16x16x32.
// Block = 4 waves = 64 rows. Both operands staged in LDS in exact fragment
// order. X staging: coalesced float4 global reads; per-(kt,q) LDS rows padded
// +16B so the bf16-pack writes are <=4-way banked. A/B reads: ds_read_b128 at
// lane*16B (m97-class pattern). Layouts verified in round 4 (passed).
// ---------------------------------------------------------------------------
__global__ __launch_bounds__(256) void gemm_kernel(const float* __restrict__ x,
                                                   const float* __restrict__ w,
                                                   float* __restrict__ pre) {
    __shared__ __align__(16) unsigned short wt[8 * 4 * 64 * 8];   // 32 KB, B-frag order
    __shared__ __align__(16) unsigned short xs[4][8][4][136];     // 34 KB, A-frag order (+8 shorts pad)

    const int tid = threadIdx.x;

    // ---- W staging (as round 4, proven) ----
    for (int i = tid; i < IN_DIM * OUT_DIM; i += 256) {
        const int k = i >> 6, n = i & 63;
        const int kt = k >> 5, q = (k >> 3) & 3, j = k & 7;
        const int t = n >> 4, l = n & 15;
        wt[((kt * 4 + t) * 64 + q * 16 + l) * 8 + j] = f32_to_bf16(w[i]);
    }

    // ---- X staging: 64 rows x 256 cols, coalesced float4 reads ----
    const int R0 = blockIdx.x * 64;
    #pragma unroll
    for (int it = 0; it < 16; ++it) {
        const int flatv = it * 256 + tid;        // float4 index in 64x256 tile
        const int r  = flatv >> 6;               // row in tile (64 f32x4 per row)
        const int k4 = (flatv & 63) * 4;         // first k of this float4
        int gr = R0 + r; gr = gr < N_NODES ? gr : N_NODES - 1;
        f32x4 xv = *(const f32x4*)(x + (size_t)gr * IN_DIM + k4);
        const int kt = k4 >> 5, q = (k4 >> 3) & 3, j = k4 & 7;   // j in {0,4}
        u16x4 pk;
        pk[0] = f32_to_bf16(xv.x); pk[1] = f32_to_bf16(xv.y);
        pk[2] = f32_to_bf16(xv.z); pk[3] = f32_to_bf16(xv.w);
        *(u16x4*)&xs[r >> 4][kt][q][(r & 15) * 8 + j] = pk;
    }
    __syncthreads();

    const int wave = tid >> 6;
    const int lane = tid & 63;
    const int ln16 = lane & 15;
    const int quad = lane >> 4;

    f32x4 acc[4] = {};

    #pragma unroll
    for (int kt = 0; kt < 8; ++kt) {
        bf16x8 a = *(const bf16x8*)&xs[wave][kt][quad][ln16 * 8];
        #pragma unroll
        for (int t = 0; t < 4; ++t) {
            bf16x8 b = *(const bf16x8*)(&wt[((kt * 4 + t) * 64 + lane) * 8]);
            acc[t] = __builtin_amdgcn_mfma_f32_16x16x32_bf16(a, b, acc[t], 0, 0, 0);
        }
    }

    // C/D: col = lane&15, row = quad*4 + reg
    const int rbase = R0 + wave * 16 + quad * 4;
    #pragma unroll
    for (int t = 0; t < 4; ++t) {
        #pragma unroll
        for (int r = 0; r < 4; ++r) {
            const int rr = rbase + r;
            if (rr < N_NODES)
                pre[(size_t)rr * OUT_DIM + t * 16 + ln16] = acc[t][r];
        }
    }
}

// ---------------------------------------------------------------------------
// CSR build: histogram -> 3-phase exclusive scan -> ticketed reorder
// ---------------------------------------------------------------------------
__global__ __launch_bounds__(256) void hist_kernel(const int* __restrict__ rows,
                                                   int* __restrict__ deg) {
    const int e = blockIdx.x * 256 + threadIdx.x;
    if (e < N_EDGES) atomicAdd(&deg[rows[e]], 1);
}

__global__ __launch_bounds__(256) void scan1_kernel(const int* __restrict__ deg,
                                                    int* __restrict__ off,
                                                    int* __restrict__ bsum) {
    __shared__ int s[256];
    const int t = threadIdx.x;
    const int base = blockIdx.x * 1024 + t * 4;
    int d[4];
    #pragma unroll
    for (int q = 0; q < 4; ++q) {
        const int i = base + q;
        d[q] = i < N_NODES ? deg[i] : 0;
    }
    const int tsum = d[0] + d[1] + d[2] + d[3];
    s[t] = tsum;
    __syncthreads();
    #pragma unroll
    for (int o = 1; o < 256; o <<= 1) {
        const int add = t >= o ? s[t - o] : 0;
        __syncthreads();
        s[t] += add;
        __syncthreads();
    }
    int run = t > 0 ? s[t - 1] : 0;            // exclusive prefix of tsums
    #pragma unroll
    for (int q = 0; q < 4; ++q) {
        const int i = base + q;
        if (i < N_NODES) off[i] = run;          // block-local exclusive
        run += d[q];
    }
    if (t == 255) bsum[blockIdx.x] = run;       // block total
}

__global__ __launch_bounds__(128) void scan2_kernel(const int* __restrict__ bsum,
                                                    int* __restrict__ boff,
                                                    int* __restrict__ off) {
    __shared__ int s[128];
    const int t = threadIdx.x;
    const int v = t < NB1 ? bsum[t] : 0;
    s[t] = v;
    __syncthreads();
    #pragma unroll
    for (int o = 1; o < 128; o <<= 1) {
        const int add = t >= o ? s[t - o] : 0;
        __syncthreads();
        s[t] += add;
        __syncthreads();
    }
    if (t < NB1) boff[t] = t > 0 ? s[t - 1] : 0;
    if (t == 127) off[N_NODES] = s[127];        // grand total == N_EDGES
}

__global__ __launch_bounds__(256) void scan3_kernel(int* __restrict__ off,
                                                    const int* __restrict__ boff) {
    const int i = blockIdx.x * 256 + threadIdx.x;
    if (i < N_NODES) off[i] += boff[i >> 10];
}

__global__ __launch_bounds__(256) void reorder_kernel(const int* __restrict__ rows,
                                                      const int* __restrict__ cols,
                                                      const float* __restrict__ vals,
                                                      int* __restrict__ cursor,
                                                      int2* __restrict__ epack) {
    const int e = blockIdx.x * 256 + threadIdx.x;
    if (e < N_EDGES) {
        const int r = rows[e];
        const int slot = atomicAdd(&cursor[r], 1);
        epack[slot] = make_int2(cols[e], __float_as_int(vals[e]));
    }
}

// ---------------------------------------------------------------------------
// Gather: one wave per node, lane = dim. Sequential fp32 accumulate over the
// node's CSR range (2-deep unroll for MLP), fused bias + ReLU. Zero atomics.
// ---------------------------------------------------------------------------
__global__ __launch_bounds__(256) void gather_kernel(const int* __restrict__ off,
                                                     const int2* __restrict__ epack,
                                                     const float* __restrict__ pre,
                                                     const float* __restrict__ bias,
                                                     float* __restrict__ out) {
    const int v = blockIdx.x * 4 + (threadIdx.x >> 6);
    const int j = threadIdx.x & 63;
    if (v >= N_NODES) return;
    const int s = off[v];
    const int e = off[v + 1];
    float acc = 0.0f;
    int i = s;
    for (; i + 2 <= e; i += 2) {
        const int2 e0 = epack[i];
        const int2 e1 = epack[i + 1];
        const float p0 = pre[(size_t)e0.x * OUT_DIM + j];
        const float p1 = pre[(size_t)e1.x * OUT_DIM + j];
        acc = fmaf(p0, __int_as_float(e0.y), acc);
        acc = fmaf(p1, __int_as_float(e1.y), acc);
    }
    if (i < e) {
        const int2 e0 = epack[i];
        acc = fmaf(pre[(size_t)e0.x * OUT_DIM + j], __int_as_float(e0.y), acc);
    }
    const float r = acc + bias[j];
    out[(size_t)v * OUT_DIM + j] = r > 0.0f ? r : 0.0f;
}

extern "C" void kernel_launch(void* const* d_in, const int* in_sizes, int n_in,
                              void* d_out, int out_size, void* d_ws, size_t ws_size,
                              hipStream_t stream) {
    const float* x    = (const float*)d_in[0];
    const int* rows   = (const int*)d_in[1];
    const int* cols   = (const int*)d_in[2];
    const float* vals = (const float*)d_in[3];
    const float* w    = (const float*)d_in[4];
    const float* bias = (const float*)d_in[5];
    float* out        = (float*)d_out;

    // workspace carve-up (~37 MB total)
    float* pre  = (float*)d_ws;                          // 25.6 MB
    int* deg    = (int*)(pre + (size_t)N_NODES * OUT_DIM);
    int* off    = deg + N_NODES;                         // 100002 ints (even pad)
    int* cursor = off + N_NODES + 2;
    int* bsum   = cursor + N_NODES;                      // 128
    int* boff   = bsum + 128;                            // 128
    int2* epack = (int2*)(boff + 128);                   // 10.24 MB, 8B-aligned

    hipMemsetAsync(deg, 0, N_NODES * sizeof(int), stream);

    gemm_kernel<<<(N_NODES + 63) / 64, 256, 0, stream>>>(x, w, pre);

    hist_kernel<<<(N_EDGES + 255) / 256, 256, 0, stream>>>(rows, deg);
    scan1_kernel<<<NB1, 256, 0, stream>>>(deg, off, bsum);
    scan2_kernel<<<1, 128, 0, stream>>>(bsum, boff, off);
    scan3_kernel<<<(N_NODES + 255) / 256, 256, 0, stream>>>(off, boff);

    hipMemcpyAsync(cursor, off, N_NODES * sizeof(int),
                   hipMemcpyDeviceToDevice, stream);

    reorder_kernel<<<(N_EDGES + 255) / 256, 256, 0, stream>>>(rows, cols, vals, cursor, epack);

    gather_kernel<<<(N_NODES + 3) / 4, 256, 0, stream>>>(off, epack, pre, bias, out);
}